// Round 11
// baseline (278.910 us; speedup 1.0000x reference)
//
#include <hip/hip_runtime.h>
#include <math.h>

#define D 64
#define B 64
#define NPB 128      // nodes per att block
#define NSLOT 4
#define SCAN_BS 1024
#define GR 128       // CSR slots per wave in gather

__device__ __forceinline__ unsigned encf(float x) {
  unsigned u = __float_as_uint(x);
  return (u & 0x80000000u) ? ~u : (u | 0x80000000u);
}
__device__ __forceinline__ float decf(unsigned e) {
  return (e & 0x80000000u) ? __uint_as_float(e ^ 0x80000000u) : __uint_as_float(~e);
}
__device__ __forceinline__ float sigm(float x) { return 1.0f / (1.0f + __expf(-x)); }

// ---------------- LSTM body (shared by merged + standalone kernels) ---------

__device__ __forceinline__ void lstm_body(int side, int b, int first,
    float* __restrict__ h2, float* __restrict__ c2,
    float* __restrict__ s2, float* __restrict__ r2,
    unsigned* __restrict__ m2, float* __restrict__ off2,
    const float* __restrict__ nWih, const float* __restrict__ nWhh,
    const float* __restrict__ nbih, const float* __restrict__ nbhh,
    const float* __restrict__ eWih, const float* __restrict__ eWhh,
    const float* __restrict__ ebih, const float* __restrict__ ebhh,
    float* sq, float* sg) {       // shared scratch: sq[2D], sg[4D]
  const float* Wih = side ? eWih : nWih;
  const float* Whh = side ? eWhh : nWhh;
  const float* bih = side ? ebih : nbih;
  const float* bhh = side ? ebhh : nbhh;
  float* h = h2 + side * B * D;
  float* c = c2 + side * B * D;
  float* s_buf = s2 + side * B;
  float* r_buf = r2 + side * B * D;

  int j = threadIdx.x;
  if (j < D) {
    sq[j] = h[b * D + j];
  } else if (j < 2 * D) {
    sq[j] = first ? 0.0f : (r_buf[b * D + (j - D)] / s_buf[b]);
  }
  __syncthreads();
  float acc = bih[j] + bhh[j];
  const float* wr = Wih + (size_t)j * (2 * D);
  #pragma unroll 8
  for (int k = 0; k < 2 * D; ++k) acc += sq[k] * wr[k];
  const float* wr2 = Whh + (size_t)j * D;
  #pragma unroll 8
  for (int k = 0; k < D; ++k) acc += sq[k] * wr2[k];
  sg[j] = acc;
  __syncthreads();
  if (j < D) {
    float ig = sigm(sg[j]);
    float fg = sigm(sg[D + j]);
    float gg = tanhf(sg[2 * D + j]);
    float og = sigm(sg[3 * D + j]);
    float cn = fg * c[b * D + j] + ig * gg;
    c[b * D + j] = cn;
    h[b * D + j] = og * tanhf(cn);
    r_buf[b * D + j] = 0.0f;
  }
  if (j == D) s_buf[b] = 0.0f;
  if (j == D + 1) {
    int idx = side * B + b;
    off2[idx] = first ? 0.0f : decf(m2[idx]);   // exact: const offset cancels in alpha
    m2[idx] = 0u;
  }
}

// ---------------- CSR build ----------------

// merged: blocks [0,DEG) degree histogram; [DEG, DEG+128) LSTM it0 both sides
__global__ void k_deg_lstm(int DEG, const int* __restrict__ edge_dst, int* __restrict__ deg, int E,
                           float* __restrict__ h2, float* __restrict__ c2,
                           float* __restrict__ s2, float* __restrict__ r2,
                           unsigned* __restrict__ m2, float* __restrict__ off2,
                           const float* __restrict__ nWih, const float* __restrict__ nWhh,
                           const float* __restrict__ nbih, const float* __restrict__ nbhh,
                           const float* __restrict__ eWih, const float* __restrict__ eWhh,
                           const float* __restrict__ ebih, const float* __restrict__ ebhh) {
  __shared__ float sq[2 * D], sg[4 * D];
  int bx = blockIdx.x;
  if (bx < DEG) {
    int i = bx * 256 + threadIdx.x;
    if (i < E) atomicAdd(&deg[edge_dst[i]], 1);
  } else {
    int j = bx - DEG;            // 0..127
    lstm_body(j >> 6, j & 63, 1, h2, c2, s2, r2, m2, off2,
              nWih, nWhh, nbih, nbhh, eWih, eWhh, ebih, ebhh, sq, sg);
  }
}

__global__ void k_scan1(const int* __restrict__ deg, int* __restrict__ row_start,
                        int* __restrict__ blocksum, int N) {
  __shared__ int sm[SCAN_BS];
  int t = threadIdx.x;
  int base = blockIdx.x * SCAN_BS;
  int v = (base + t < N) ? deg[base + t] : 0;
  sm[t] = v;
  __syncthreads();
  for (int ofs = 1; ofs < SCAN_BS; ofs <<= 1) {
    int add = (t >= ofs) ? sm[t - ofs] : 0;
    __syncthreads();
    sm[t] += add;
    __syncthreads();
  }
  if (base + t < N) row_start[base + t] = sm[t] - v;   // block-local exclusive
  if (t == SCAN_BS - 1) blocksum[blockIdx.x] = sm[t];
}

// scan3 with inline scan of blocksum (removes old scan2 dispatch)
__global__ void k_scan3(int* __restrict__ row_start, const int* __restrict__ blocksum,
                        int* __restrict__ cursor, int N, int nb) {
  __shared__ int sm[128];
  int t = threadIdx.x;
  if (t < 128) sm[t] = (t < nb) ? blocksum[t] : 0;
  __syncthreads();
  for (int ofs = 1; ofs < 128; ofs <<= 1) {
    int add = (t < 128 && t >= ofs) ? sm[t - ofs] : 0;
    __syncthreads();
    if (t < 128) sm[t] += add;
    __syncthreads();
  }
  int n = blockIdx.x * 256 + t;
  if (n < N) {
    int c = n / SCAN_BS;
    int v = row_start[n] + ((c > 0) ? sm[c - 1] : 0);
    row_start[n] = v;
    cursor[n] = v;
  }
}

__global__ void k_fill(const int* __restrict__ edge_dst, int* __restrict__ cursor,
                       int* __restrict__ csr, int* __restrict__ csr_dst, int E) {
  int e = blockIdx.x * blockDim.x + threadIdx.x;
  if (e < E) {
    int dst = edge_dst[e];
    int idx = atomicAdd(&cursor[dst], 1);
    csr[idx] = e;
    csr_dst[idx] = dst;
  }
}

// ---------------- edge-centric segmented gather ----------------
// One 64-lane wave owns GR consecutive CSR slots; lane = feature dim.
// Every efeat row load is one fully-used coalesced 256B transaction.
// Interior segments -> plain store (exclusive by sortedness);
// first/last segment of each wave range -> atomicAdd onto zero-init.
__global__ void k_gather(const float* __restrict__ efeat, const int* __restrict__ csr,
                         const int* __restrict__ csr_dst, float* __restrict__ edge_agg, int E) {
  __shared__ int s_id[4 * GR], s_d[4 * GR];
  int tid = threadIdx.x;
  int bbase = blockIdx.x * (4 * GR);
  #pragma unroll
  for (int q = 0; q < 2; ++q) {
    int p = tid + q * 256;
    int gi = bbase + p;
    if (gi < E) { s_id[p] = csr[gi]; s_d[p] = csr_dst[gi]; }
    else        { s_id[p] = 0;       s_d[p] = -1; }
  }
  __syncthreads();
  int wave = tid >> 6, lane = tid & 63;
  int wbase = wave * GR;
  float acc = 0.0f;
  int cur = s_d[wbase];
  bool firstSeg = true;
  for (int j8 = 0; j8 < GR; j8 += 8) {
    float v[8]; int d[8];
    #pragma unroll
    for (int jj = 0; jj < 8; ++jj) {
      int p = wbase + j8 + jj;
      d[jj] = s_d[p];
      v[jj] = efeat[(size_t)s_id[p] * D + lane];
    }
    #pragma unroll
    for (int jj = 0; jj < 8; ++jj) {
      if (d[jj] != cur) {
        if (cur >= 0) {
          if (firstSeg) atomicAdd(&edge_agg[(size_t)cur * D + lane], acc);
          else          edge_agg[(size_t)cur * D + lane] = acc;
        }
        firstSeg = false;
        cur = d[jj];
        acc = 0.0f;
      }
      acc += (d[jj] >= 0) ? v[jj] : 0.0f;
    }
  }
  if (cur >= 0) atomicAdd(&edge_agg[(size_t)cur * D + lane], acc);  // tail = boundary
}

// divide by deg (0 for isolated nodes)
__global__ void k_div(float* __restrict__ edge_agg, const int* __restrict__ deg, int N) {
  int idx = blockIdx.x * blockDim.x + threadIdx.x;
  int n = idx >> 4, l16 = idx & 15;
  if (n >= N) return;
  int dg = deg[n];
  float4* p = (float4*)(edge_agg + (size_t)n * D + l16 * 4);
  if (dg > 0) {
    float inv = 1.0f / (float)dg;
    float4 v = *p;
    v.x *= inv; v.y *= inv; v.z *= inv; v.w *= inv;
    *p = v;
  } else {
    *p = make_float4(0.f, 0.f, 0.f, 0.f);
  }
}

// ---------------- standalone LSTM (both sides, grid (B,2)) -------------------

__global__ void k_lstm2(int first, float* __restrict__ h2, float* __restrict__ c2,
                        float* __restrict__ s2, float* __restrict__ r2,
                        unsigned* __restrict__ m2, float* __restrict__ off2,
                        const float* __restrict__ nWih, const float* __restrict__ nWhh,
                        const float* __restrict__ nbih, const float* __restrict__ nbhh,
                        const float* __restrict__ eWih, const float* __restrict__ eWhh,
                        const float* __restrict__ ebih, const float* __restrict__ ebhh) {
  __shared__ float sq[2 * D], sg[4 * D];
  lstm_body(blockIdx.y, blockIdx.x, first, h2, c2, s2, r2, m2, off2,
            nWih, nWhh, nbih, nbhh, eWih, eWhh, ebih, ebhh, sq, sg);
}

// ---------------- fused one-pass attention (both sides via blockIdx.y) -------

__global__ void k_att_fused(const float* __restrict__ feat, const float* __restrict__ edge_agg,
                            const int* __restrict__ gid, const float* __restrict__ h2,
                            const float* __restrict__ off2, unsigned* __restrict__ m2,
                            float* __restrict__ s2, float* __restrict__ r2, int N) {
  __shared__ float r_lds[16 * NSLOT * D];   // 16KB
  __shared__ float s_lds[16 * NSLOT];
  __shared__ float m_lds[16 * NSLOT];
  __shared__ float h_lds[NSLOT * D];
  __shared__ float o_lds[NSLOT];
  __shared__ int sg_first;
  __shared__ int used[NSLOT];

  int side = blockIdx.y;
  const float* F = side ? edge_agg : feat;
  const float* h = h2 + side * B * D;
  const float* off = off2 + side * B;
  unsigned* m_enc = m2 + side * B;
  float* s_buf = s2 + side * B;
  float* r_buf = r2 + side * B * D;

  int tid = threadIdx.x;
  int grp = tid >> 4;
  int d4  = tid & 15;
  int base = blockIdx.x * NPB;

  for (int i = tid; i < 16 * NSLOT * D; i += 256) r_lds[i] = 0.0f;
  if (tid < 16 * NSLOT) { s_lds[tid] = 0.0f; m_lds[tid] = -3.4e38f; }
  if (tid < NSLOT) used[tid] = 0;
  if (tid == 0) sg_first = gid[base];
  __syncthreads();
  int gfirst = sg_first;
  {
    int slot = tid >> 6, dim = tid & 63;
    int g = gfirst + slot;
    if (g < B) {
      h_lds[tid] = h[g * D + dim];
      if (dim == 0) o_lds[slot] = off[g];
    }
  }
  __syncthreads();

  float4 acc = make_float4(0.f, 0.f, 0.f, 0.f);
  float sum_ex = 0.0f;
  float local_max = -3.4e38f;
  int cur_g = -1;

  for (int it = 0; it < NPB / 32; ++it) {
    int n0 = base + it * 32 + grp;
    int n1 = n0 + 16;
    bool ok0 = n0 < N, ok1 = n1 < N;
    int g0 = ok0 ? gid[n0] : -1;
    int g1 = ok1 ? gid[n1] : -1;
    float4 f0 = make_float4(0,0,0,0), f1 = make_float4(0,0,0,0);
    float dot0 = 0.f, dot1 = 0.f, ex0 = 0.f, ex1 = 0.f;
    if (ok0) {
      f0 = *(const float4*)(F + (size_t)n0 * D + d4 * 4);
      int s0 = g0 - gfirst;
      float4 hv = (s0 >= 0 && s0 < NSLOT) ? *(const float4*)&h_lds[(s0 << 6) + (d4 << 2)]
                                          : *(const float4*)(h + (size_t)g0 * D + d4 * 4);
      dot0 = f0.x * hv.x + f0.y * hv.y + f0.z * hv.z + f0.w * hv.w;
    }
    if (ok1) {
      f1 = *(const float4*)(F + (size_t)n1 * D + d4 * 4);
      int s1 = g1 - gfirst;
      float4 hv = (s1 >= 0 && s1 < NSLOT) ? *(const float4*)&h_lds[(s1 << 6) + (d4 << 2)]
                                          : *(const float4*)(h + (size_t)g1 * D + d4 * 4);
      dot1 = f1.x * hv.x + f1.y * hv.y + f1.z * hv.z + f1.w * hv.w;
    }
    dot0 += __shfl_xor(dot0, 1); dot1 += __shfl_xor(dot1, 1);
    dot0 += __shfl_xor(dot0, 2); dot1 += __shfl_xor(dot1, 2);
    dot0 += __shfl_xor(dot0, 4); dot1 += __shfl_xor(dot1, 4);
    dot0 += __shfl_xor(dot0, 8); dot1 += __shfl_xor(dot1, 8);
    if (ok0) {
      int s0 = g0 - gfirst;
      ex0 = __expf(dot0 - ((s0 >= 0 && s0 < NSLOT) ? o_lds[s0] : off[g0]));
    }
    if (ok1) {
      int s1 = g1 - gfirst;
      ex1 = __expf(dot1 - ((s1 >= 0 && s1 < NSLOT) ? o_lds[s1] : off[g1]));
    }

    #pragma unroll
    for (int pair = 0; pair < 2; ++pair) {
      bool ok = pair ? ok1 : ok0;
      int g = pair ? g1 : g0;
      float ex = pair ? ex1 : ex0;
      float dt = pair ? dot1 : dot0;
      float4 f = pair ? f1 : f0;
      if (!ok) continue;
      if (g != cur_g) {
        if (cur_g >= 0) {
          int slot = cur_g - gfirst;
          if (slot >= 0 && slot < NSLOT) {
            float4* p = (float4*)&r_lds[((grp * NSLOT + slot) << 6) + (d4 << 2)];
            float4 v = *p;
            v.x += acc.x; v.y += acc.y; v.z += acc.z; v.w += acc.w;
            *p = v;
            if (d4 == 0) {
              s_lds[grp * NSLOT + slot] += sum_ex;
              m_lds[grp * NSLOT + slot] = fmaxf(m_lds[grp * NSLOT + slot], local_max);
              used[slot] = 1;
            }
          } else {
            float* rp = r_buf + cur_g * D + d4 * 4;
            atomicAdd(rp + 0, acc.x); atomicAdd(rp + 1, acc.y);
            atomicAdd(rp + 2, acc.z); atomicAdd(rp + 3, acc.w);
            if (d4 == 0) { atomicAdd(&s_buf[cur_g], sum_ex); atomicMax(&m_enc[cur_g], encf(local_max)); }
          }
        }
        cur_g = g; acc = make_float4(0,0,0,0); sum_ex = 0.f; local_max = -3.4e38f;
      }
      acc.x += ex * f.x; acc.y += ex * f.y; acc.z += ex * f.z; acc.w += ex * f.w;
      if (d4 == 0) { sum_ex += ex; local_max = fmaxf(local_max, dt); }
    }
  }
  // tail flush
  if (cur_g >= 0) {
    int slot = cur_g - gfirst;
    if (slot >= 0 && slot < NSLOT) {
      float4* p = (float4*)&r_lds[((grp * NSLOT + slot) << 6) + (d4 << 2)];
      float4 v = *p;
      v.x += acc.x; v.y += acc.y; v.z += acc.z; v.w += acc.w;
      *p = v;
      if (d4 == 0) {
        s_lds[grp * NSLOT + slot] += sum_ex;
        m_lds[grp * NSLOT + slot] = fmaxf(m_lds[grp * NSLOT + slot], local_max);
        used[slot] = 1;
      }
    } else {
      float* rp = r_buf + cur_g * D + d4 * 4;
      atomicAdd(rp + 0, acc.x); atomicAdd(rp + 1, acc.y);
      atomicAdd(rp + 2, acc.z); atomicAdd(rp + 3, acc.w);
      if (d4 == 0) { atomicAdd(&s_buf[cur_g], sum_ex); atomicMax(&m_enc[cur_g], encf(local_max)); }
    }
  }
  __syncthreads();

  // block-level reduction
  {
    int slot = tid >> 6, dim = tid & 63;
    int g = gfirst + slot;
    if (g < B && used[slot]) {
      float sum = 0.0f;
      #pragma unroll
      for (int q = 0; q < 16; ++q) sum += r_lds[((q * NSLOT + slot) << 6) + dim];
      atomicAdd(&r_buf[g * D + dim], sum);
    }
  }
  if (tid < NSLOT) {
    int g = gfirst + tid;
    if (g < B && used[tid]) {
      float ssum = 0.0f;
      #pragma unroll
      for (int q = 0; q < 16; ++q) ssum += s_lds[q * NSLOT + tid];
      atomicAdd(&s_buf[g], ssum);
    }
  } else if (tid >= 64 && tid < 64 + NSLOT) {
    int slot = tid - 64;
    int g = gfirst + slot;
    if (g < B && used[slot]) {
      float mmax = -3.4e38f;
      #pragma unroll
      for (int q = 0; q < 16; ++q) mmax = fmaxf(mmax, m_lds[q * NSLOT + slot]);
      atomicMax(&m_enc[g], encf(mmax));
    }
  }
}

// ---------------- MLP ----------------

__global__ void k_mlp(const float* __restrict__ h2, const float* __restrict__ r2,
                      const float* __restrict__ s2,
                      const float* __restrict__ W1, const float* __restrict__ b1,
                      const float* __restrict__ W2, const float* __restrict__ b2,
                      const float* __restrict__ W3, const float* __restrict__ b3,
                      float* __restrict__ out) {
  __shared__ float x[4 * D], h1[32], h2s[16];
  int b = blockIdx.x, t = threadIdx.x;   // 128 threads
  x[t]       = (t < D) ? h2[b * D + t]         : r2[b * D + (t - D)] / s2[b];
  x[128 + t] = (t < D) ? h2[B * D + b * D + t] : r2[B * D + b * D + (t - D)] / s2[B + b];
  __syncthreads();
  if (t < 32) {
    float acc = b1[t];
    const float* w = W1 + (size_t)t * (4 * D);
    #pragma unroll 8
    for (int k = 0; k < 4 * D; ++k) acc += x[k] * w[k];
    h1[t] = fmaxf(acc, 0.0f);
  }
  __syncthreads();
  if (t < 16) {
    float acc = b2[t];
    const float* w = W2 + (size_t)t * 32;
    #pragma unroll
    for (int k = 0; k < 32; ++k) acc += h1[k] * w[k];
    h2s[t] = fmaxf(acc, 0.0f);
  }
  __syncthreads();
  if (t == 0) {
    float acc = b3[0];
    #pragma unroll
    for (int k = 0; k < 16; ++k) acc += h2s[k] * W3[k];
    out[b] = acc;
  }
}

// ---------------- driver ----------------

extern "C" void kernel_launch(void* const* d_in, const int* in_sizes, int n_in,
                              void* d_out, int out_size, void* d_ws, size_t ws_size,
                              hipStream_t stream) {
  const float* feat      = (const float*)d_in[0];
  const float* efeat     = (const float*)d_in[1];
  const int*   edge_dst  = (const int*)d_in[2];
  const int*   node_graph= (const int*)d_in[3];
  const float* node_Wih  = (const float*)d_in[5];
  const float* node_Whh  = (const float*)d_in[6];
  const float* node_bih  = (const float*)d_in[7];
  const float* node_bhh  = (const float*)d_in[8];
  const float* edge_Wih  = (const float*)d_in[9];
  const float* edge_Whh  = (const float*)d_in[10];
  const float* edge_bih  = (const float*)d_in[11];
  const float* edge_bhh  = (const float*)d_in[12];
  const float* W1 = (const float*)d_in[13];
  const float* b1 = (const float*)d_in[14];
  const float* W2 = (const float*)d_in[15];
  const float* b2 = (const float*)d_in[16];
  const float* W3 = (const float*)d_in[17];
  const float* b3 = (const float*)d_in[18];
  float* out = (float*)d_out;

  const int N = in_sizes[0] / D;
  const int E = in_sizes[2];

  // ws layout: zero-region first (edge_agg, h2, c2, deg) for ONE memset
  float* ws = (float*)d_ws;
  size_t off = 0;
  float* edge_agg = ws + off; off += (size_t)N * D;       // zeroed
  float* h2       = ws + off; off += 2 * B * D;           // zeroed
  float* c2       = ws + off; off += 2 * B * D;           // zeroed
  int* deg        = (int*)(ws + off); off += N;           // zeroed
  float* s2       = ws + off; off += 2 * B;
  float* r2       = ws + off; off += 2 * B * D;
  float* off2     = ws + off; off += 2 * B;
  unsigned* m2    = (unsigned*)(ws + off); off += 2 * B;
  int* row_start  = (int*)(ws + off); off += N;
  int* cursor     = (int*)(ws + off); off += N;
  int* blocksum   = (int*)(ws + off); off += 128;
  int* csr        = (int*)(ws + off); off += E + 8;
  int* csr_dst    = (int*)(ws + off); off += E + 8;

  hipMemsetAsync(ws, 0, ((size_t)N * D + 4 * B * D + N) * sizeof(float), stream);

  const int nb  = (N + SCAN_BS - 1) / SCAN_BS;
  const int DEG = (E + 255) / 256;
  const int ATT = (N + NPB - 1) / NPB;

  // CSR build (deg merged with both-side LSTM it0)
  k_deg_lstm<<<DEG + 128, 256, 0, stream>>>(DEG, edge_dst, deg, E, h2, c2, s2, r2, m2, off2,
      node_Wih, node_Whh, node_bih, node_bhh, edge_Wih, edge_Whh, edge_bih, edge_bhh);
  k_scan1<<<nb, SCAN_BS, 0, stream>>>(deg, row_start, blocksum, N);
  k_scan3<<<(N + 255) / 256, 256, 0, stream>>>(row_start, blocksum, cursor, N, nb);
  k_fill<<<DEG, 256, 0, stream>>>(edge_dst, cursor, csr, csr_dst, E);

  // edge-centric segmented gather + divide
  k_gather<<<(E + 4 * GR - 1) / (4 * GR), 256, 0, stream>>>(efeat, csr, csr_dst, edge_agg, E);
  {
    long long tot = (long long)N * 16;
    k_div<<<(int)((tot + 255) / 256), 256, 0, stream>>>(edge_agg, deg, N);
  }

  // set2set loop (LSTM it0 already done in k_deg_lstm)
  dim3 ga(ATT, 2), gb(B, 2);
  k_att_fused<<<ga, 256, 0, stream>>>(feat, edge_agg, node_graph, h2, off2, m2, s2, r2, N);
  for (int it = 1; it < 3; ++it) {
    k_lstm2<<<gb, 256, 0, stream>>>(0, h2, c2, s2, r2, m2, off2,
                                    node_Wih, node_Whh, node_bih, node_bhh,
                                    edge_Wih, edge_Whh, edge_bih, edge_bhh);
    k_att_fused<<<ga, 256, 0, stream>>>(feat, edge_agg, node_graph, h2, off2, m2, s2, r2, N);
  }

  k_mlp<<<B, 128, 0, stream>>>(h2, r2, s2, W1, b1, W2, b2, W3, b3, out);
}

// Round 12
// 276.941 us; speedup vs baseline: 1.0071x; 1.0071x over previous
//
#include <hip/hip_runtime.h>
#include <math.h>

#define D 64
#define B 64
#define NPB 128      // nodes per att block
#define NSLOT 4
#define SCAN_BS 1024

__device__ __forceinline__ unsigned encf(float x) {
  unsigned u = __float_as_uint(x);
  return (u & 0x80000000u) ? ~u : (u | 0x80000000u);
}
__device__ __forceinline__ float decf(unsigned e) {
  return (e & 0x80000000u) ? __uint_as_float(e ^ 0x80000000u) : __uint_as_float(~e);
}
__device__ __forceinline__ float sigm(float x) { return 1.0f / (1.0f + __expf(-x)); }

// ---------------- LSTM body ----------------

__device__ __forceinline__ void lstm_body(int side, int b, int first,
    float* __restrict__ h2, float* __restrict__ c2,
    float* __restrict__ s2, float* __restrict__ r2,
    unsigned* __restrict__ m2, float* __restrict__ off2,
    const float* __restrict__ nWih, const float* __restrict__ nWhh,
    const float* __restrict__ nbih, const float* __restrict__ nbhh,
    const float* __restrict__ eWih, const float* __restrict__ eWhh,
    const float* __restrict__ ebih, const float* __restrict__ ebhh,
    float* sq, float* sg) {
  const float* Wih = side ? eWih : nWih;
  const float* Whh = side ? eWhh : nWhh;
  const float* bih = side ? ebih : nbih;
  const float* bhh = side ? ebhh : nbhh;
  float* h = h2 + side * B * D;
  float* c = c2 + side * B * D;
  float* s_buf = s2 + side * B;
  float* r_buf = r2 + side * B * D;

  int j = threadIdx.x;
  if (j < D) {
    sq[j] = h[b * D + j];
  } else if (j < 2 * D) {
    sq[j] = first ? 0.0f : (r_buf[b * D + (j - D)] / s_buf[b]);
  }
  __syncthreads();
  float acc = bih[j] + bhh[j];
  const float* wr = Wih + (size_t)j * (2 * D);
  #pragma unroll 8
  for (int k = 0; k < 2 * D; ++k) acc += sq[k] * wr[k];
  const float* wr2 = Whh + (size_t)j * D;
  #pragma unroll 8
  for (int k = 0; k < D; ++k) acc += sq[k] * wr2[k];
  sg[j] = acc;
  __syncthreads();
  if (j < D) {
    float ig = sigm(sg[j]);
    float fg = sigm(sg[D + j]);
    float gg = tanhf(sg[2 * D + j]);
    float og = sigm(sg[3 * D + j]);
    float cn = fg * c[b * D + j] + ig * gg;
    c[b * D + j] = cn;
    h[b * D + j] = og * tanhf(cn);
    r_buf[b * D + j] = 0.0f;
  }
  if (j == D) s_buf[b] = 0.0f;
  if (j == D + 1) {
    int idx = side * B + b;
    off2[idx] = first ? 0.0f : decf(m2[idx]);   // exact: const offset cancels in alpha
    m2[idx] = 0u;
  }
}

// ---------------- CSR build ----------------

// merged: blocks [0,DEG) degree histogram; [DEG, DEG+128) LSTM it0 both sides
__global__ void k_deg_lstm(int DEG, const int* __restrict__ edge_dst, int* __restrict__ deg, int E,
                           float* __restrict__ h2, float* __restrict__ c2,
                           float* __restrict__ s2, float* __restrict__ r2,
                           unsigned* __restrict__ m2, float* __restrict__ off2,
                           const float* __restrict__ nWih, const float* __restrict__ nWhh,
                           const float* __restrict__ nbih, const float* __restrict__ nbhh,
                           const float* __restrict__ eWih, const float* __restrict__ eWhh,
                           const float* __restrict__ ebih, const float* __restrict__ ebhh) {
  __shared__ float sq[2 * D], sg[4 * D];
  int bx = blockIdx.x;
  if (bx < DEG) {
    int i = bx * 256 + threadIdx.x;
    if (i < E) atomicAdd(&deg[edge_dst[i]], 1);
  } else {
    int j = bx - DEG;            // 0..127
    lstm_body(j >> 6, j & 63, 1, h2, c2, s2, r2, m2, off2,
              nWih, nWhh, nbih, nbhh, eWih, eWhh, ebih, ebhh, sq, sg);
  }
}

__global__ void k_scan1(const int* __restrict__ deg, int* __restrict__ row_start,
                        int* __restrict__ blocksum, int N) {
  __shared__ int sm[SCAN_BS];
  int t = threadIdx.x;
  int base = blockIdx.x * SCAN_BS;
  int v = (base + t < N) ? deg[base + t] : 0;
  sm[t] = v;
  __syncthreads();
  for (int ofs = 1; ofs < SCAN_BS; ofs <<= 1) {
    int add = (t >= ofs) ? sm[t - ofs] : 0;
    __syncthreads();
    sm[t] += add;
    __syncthreads();
  }
  if (base + t < N) row_start[base + t] = sm[t] - v;
  if (t == SCAN_BS - 1) blocksum[blockIdx.x] = sm[t];
}

// scan3 with inline scan of blocksum
__global__ void k_scan3(int* __restrict__ row_start, const int* __restrict__ blocksum,
                        int* __restrict__ cursor, int N, int nb) {
  __shared__ int sm[128];
  int t = threadIdx.x;
  if (t < 128) sm[t] = (t < nb) ? blocksum[t] : 0;
  __syncthreads();
  for (int ofs = 1; ofs < 128; ofs <<= 1) {
    int add = (t < 128 && t >= ofs) ? sm[t - ofs] : 0;
    __syncthreads();
    if (t < 128) sm[t] += add;
    __syncthreads();
  }
  int n = blockIdx.x * 256 + t;
  if (n < N) {
    int c = n / SCAN_BS;
    int v = row_start[n] + ((c > 0) ? sm[c - 1] : 0);
    row_start[n] = v;
    cursor[n] = v;
  }
}

__global__ void k_fill(const int* __restrict__ edge_dst, int* __restrict__ cursor,
                       int* __restrict__ csr, int E) {
  int e = blockIdx.x * blockDim.x + threadIdx.x;
  if (e < E) {
    int dst = edge_dst[e];
    int idx = atomicAdd(&cursor[dst], 1);
    csr[idx] = e;
  }
}

// ---------------- gather (R9 node-centric: 16-lane group/node, unroll 16) ----

__global__ void k_gather(const float* __restrict__ efeat, const int* __restrict__ csr,
                         const int* __restrict__ row_start, const int* __restrict__ deg,
                         float* __restrict__ edge_agg, int N) {
  int grp = (blockIdx.x * blockDim.x + threadIdx.x) >> 4;
  int l16 = threadIdx.x & 15;
  if (grp >= N) return;
  int base = row_start[grp];
  int dg = deg[grp];
  float4 acc = make_float4(0.f, 0.f, 0.f, 0.f);
  for (int i = 0; i < dg; i += 16) {
    int idx[16];
    #pragma unroll
    for (int j = 0; j < 16; ++j) {
      int k = i + j;
      idx[j] = csr[base + (k < dg ? k : dg - 1)];
    }
    #pragma unroll
    for (int j = 0; j < 16; ++j) {
      float4 v = *(const float4*)(efeat + (size_t)idx[j] * D + l16 * 4);
      bool ok = (i + j < dg);
      acc.x += ok ? v.x : 0.0f;
      acc.y += ok ? v.y : 0.0f;
      acc.z += ok ? v.z : 0.0f;
      acc.w += ok ? v.w : 0.0f;
    }
  }
  float inv = 1.0f / fmaxf((float)dg, 1.0f);
  acc.x *= inv; acc.y *= inv; acc.z *= inv; acc.w *= inv;
  *(float4*)(edge_agg + (size_t)grp * D + l16 * 4) = acc;
}

// ---------------- standalone LSTM (both sides, grid (B,2)) -------------------

__global__ void k_lstm2(int first, float* __restrict__ h2, float* __restrict__ c2,
                        float* __restrict__ s2, float* __restrict__ r2,
                        unsigned* __restrict__ m2, float* __restrict__ off2,
                        const float* __restrict__ nWih, const float* __restrict__ nWhh,
                        const float* __restrict__ nbih, const float* __restrict__ nbhh,
                        const float* __restrict__ eWih, const float* __restrict__ eWhh,
                        const float* __restrict__ ebih, const float* __restrict__ ebhh) {
  __shared__ float sq[2 * D], sg[4 * D];
  lstm_body(blockIdx.y, blockIdx.x, first, h2, c2, s2, r2, m2, off2,
            nWih, nWhh, nbih, nbhh, eWih, eWhh, ebih, ebhh, sq, sg);
}

// ---------------- fused attention: register slots + shfl reduction -----------
// grid (ceil(N/NPB), 2), 256 threads = 4 waves x 4 groups x 16 lanes.

__global__ void k_att_fused(const float* __restrict__ feat, const float* __restrict__ edge_agg,
                            const int* __restrict__ gid, const float* __restrict__ h2,
                            const float* __restrict__ off2, unsigned* __restrict__ m2,
                            float* __restrict__ s2, float* __restrict__ r2, int N) {
  __shared__ float h_lds[NSLOT * D];          // 1KB
  __shared__ float o_lds[NSLOT];
  __shared__ float r_lds[4][NSLOT][D];        // 4KB, write-only then read (no zeroing)
  __shared__ float s_lds[4][NSLOT];
  __shared__ float m_lds[4][NSLOT];
  __shared__ int sg_first, sg_count;

  int side = blockIdx.y;
  const float* F = side ? edge_agg : feat;
  const float* h = h2 + side * B * D;
  const float* off = off2 + side * B;
  unsigned* m_enc = m2 + side * B;
  float* s_buf = s2 + side * B;
  float* r_buf = r2 + side * B * D;

  int tid = threadIdx.x;
  int grp = tid >> 4;
  int d4  = tid & 15;
  int wave = tid >> 6;
  int lane = tid & 63;
  int base = blockIdx.x * NPB;

  if (tid == 0) {
    int gf = gid[base];
    sg_first = gf;
    sg_count = gid[min(base + NPB, N) - 1] - gf + 1;
  }
  __syncthreads();
  const int gfirst = sg_first;
  const int gcount = sg_count;
  {
    int slot = tid >> 6, dim = tid & 63;
    int g = gfirst + slot;
    if (slot < NSLOT && g < B) {
      h_lds[slot * D + dim] = h[g * D + dim];
      if (dim == 0) o_lds[slot] = off[g];
    }
  }
  __syncthreads();

  // per-slot register accumulators (flush target)
  float4 a0 = make_float4(0,0,0,0), a1 = a0, a2 = a0, a3 = a0;
  float se0 = 0.f, se1 = 0.f, se2 = 0.f, se3 = 0.f;
  float mx0 = -3.4e38f, mx1 = mx0, mx2 = mx0, mx3 = mx0;
  // running segment
  float4 acc = make_float4(0,0,0,0);
  float sum_ex = 0.f, local_max = -3.4e38f;
  int cur_g = -1;

#define FLUSH_SEG() do { \
    if (cur_g >= 0) { \
      int s_ = cur_g - gfirst; \
      if (s_ == 0)      { a0.x+=acc.x; a0.y+=acc.y; a0.z+=acc.z; a0.w+=acc.w; se0+=sum_ex; mx0=fmaxf(mx0,local_max); } \
      else if (s_ == 1) { a1.x+=acc.x; a1.y+=acc.y; a1.z+=acc.z; a1.w+=acc.w; se1+=sum_ex; mx1=fmaxf(mx1,local_max); } \
      else if (s_ == 2) { a2.x+=acc.x; a2.y+=acc.y; a2.z+=acc.z; a2.w+=acc.w; se2+=sum_ex; mx2=fmaxf(mx2,local_max); } \
      else if (s_ == 3) { a3.x+=acc.x; a3.y+=acc.y; a3.z+=acc.z; a3.w+=acc.w; se3+=sum_ex; mx3=fmaxf(mx3,local_max); } \
      else { \
        float* rp = r_buf + cur_g * D + d4 * 4; \
        atomicAdd(rp+0,acc.x); atomicAdd(rp+1,acc.y); atomicAdd(rp+2,acc.z); atomicAdd(rp+3,acc.w); \
        if (d4 == 0) { atomicAdd(&s_buf[cur_g],sum_ex); atomicMax(&m_enc[cur_g],encf(local_max)); } \
      } \
    } \
    acc = make_float4(0,0,0,0); sum_ex = 0.f; local_max = -3.4e38f; \
  } while(0)

  for (int it = 0; it < NPB / 32; ++it) {
    int n0 = base + it * 32 + grp;
    int n1 = n0 + 16;
    bool ok0 = n0 < N, ok1 = n1 < N;
    int g0 = ok0 ? gid[n0] : -1;
    int g1 = ok1 ? gid[n1] : -1;
    float4 f0 = make_float4(0,0,0,0), f1 = make_float4(0,0,0,0);
    float dot0 = 0.f, dot1 = 0.f, ex0 = 0.f, ex1 = 0.f;
    if (ok0) {
      f0 = *(const float4*)(F + (size_t)n0 * D + d4 * 4);
      int s0 = g0 - gfirst;
      float4 hv = (s0 >= 0 && s0 < NSLOT) ? *(const float4*)&h_lds[(s0 << 6) + (d4 << 2)]
                                          : *(const float4*)(h + (size_t)g0 * D + d4 * 4);
      dot0 = f0.x * hv.x + f0.y * hv.y + f0.z * hv.z + f0.w * hv.w;
    }
    if (ok1) {
      f1 = *(const float4*)(F + (size_t)n1 * D + d4 * 4);
      int s1 = g1 - gfirst;
      float4 hv = (s1 >= 0 && s1 < NSLOT) ? *(const float4*)&h_lds[(s1 << 6) + (d4 << 2)]
                                          : *(const float4*)(h + (size_t)g1 * D + d4 * 4);
      dot1 = f1.x * hv.x + f1.y * hv.y + f1.z * hv.z + f1.w * hv.w;
    }
    dot0 += __shfl_xor(dot0, 1); dot1 += __shfl_xor(dot1, 1);
    dot0 += __shfl_xor(dot0, 2); dot1 += __shfl_xor(dot1, 2);
    dot0 += __shfl_xor(dot0, 4); dot1 += __shfl_xor(dot1, 4);
    dot0 += __shfl_xor(dot0, 8); dot1 += __shfl_xor(dot1, 8);
    if (ok0) {
      int s0 = g0 - gfirst;
      ex0 = __expf(dot0 - ((s0 >= 0 && s0 < NSLOT) ? o_lds[s0] : off[g0]));
    }
    if (ok1) {
      int s1 = g1 - gfirst;
      ex1 = __expf(dot1 - ((s1 >= 0 && s1 < NSLOT) ? o_lds[s1] : off[g1]));
    }

    if (ok0) {
      if (g0 != cur_g) { FLUSH_SEG(); cur_g = g0; }
      acc.x += ex0 * f0.x; acc.y += ex0 * f0.y; acc.z += ex0 * f0.z; acc.w += ex0 * f0.w;
      if (d4 == 0) { sum_ex += ex0; local_max = fmaxf(local_max, dot0); }
    }
    if (ok1) {
      if (g1 != cur_g) { FLUSH_SEG(); cur_g = g1; }
      acc.x += ex1 * f1.x; acc.y += ex1 * f1.y; acc.z += ex1 * f1.z; acc.w += ex1 * f1.w;
      if (d4 == 0) { sum_ex += ex1; local_max = fmaxf(local_max, dot1); }
    }
  }
  FLUSH_SEG();   // tail
#undef FLUSH_SEG

  // wave-level cross-group reduction (strides 16, 32 over the 64-lane wave)
#define WRED4(A) \
    A.x += __shfl_xor(A.x, 16); A.y += __shfl_xor(A.y, 16); A.z += __shfl_xor(A.z, 16); A.w += __shfl_xor(A.w, 16); \
    A.x += __shfl_xor(A.x, 32); A.y += __shfl_xor(A.y, 32); A.z += __shfl_xor(A.z, 32); A.w += __shfl_xor(A.w, 32);
#define WRED1(S) S += __shfl_xor(S, 16); S += __shfl_xor(S, 32);
#define WREDM(M) M = fmaxf(M, __shfl_xor(M, 16)); M = fmaxf(M, __shfl_xor(M, 32));

  WRED4(a0); WRED1(se0); WREDM(mx0);
  if (gcount > 1) { WRED4(a1); WRED1(se1); WREDM(mx1); }
  if (gcount > 2) { WRED4(a2); WRED1(se2); WREDM(mx2); }
  if (gcount > 3) { WRED4(a3); WRED1(se3); WREDM(mx3); }
#undef WRED4
#undef WRED1
#undef WREDM

  if (lane < 16) {
    *(float4*)&r_lds[wave][0][lane * 4] = a0;
    if (gcount > 1) *(float4*)&r_lds[wave][1][lane * 4] = a1;
    if (gcount > 2) *(float4*)&r_lds[wave][2][lane * 4] = a2;
    if (gcount > 3) *(float4*)&r_lds[wave][3][lane * 4] = a3;
  }
  if (lane == 0) {
    s_lds[wave][0] = se0; m_lds[wave][0] = mx0;
    if (gcount > 1) { s_lds[wave][1] = se1; m_lds[wave][1] = mx1; }
    if (gcount > 2) { s_lds[wave][2] = se2; m_lds[wave][2] = mx2; }
    if (gcount > 3) { s_lds[wave][3] = se3; m_lds[wave][3] = mx3; }
  }
  __syncthreads();

  // block-level reduce over the 4 waves
  {
    int slot = tid >> 6, dim = tid & 63;
    int g = gfirst + slot;
    if (slot < gcount && g < B) {
      float sum = r_lds[0][slot][dim] + r_lds[1][slot][dim]
                + r_lds[2][slot][dim] + r_lds[3][slot][dim];
      atomicAdd(&r_buf[g * D + dim], sum);
    }
  }
  if (tid < NSLOT && tid < gcount) {
    int g = gfirst + tid;
    if (g < B) {
      float ssum = s_lds[0][tid] + s_lds[1][tid] + s_lds[2][tid] + s_lds[3][tid];
      atomicAdd(&s_buf[g], ssum);
      float mm = fmaxf(fmaxf(m_lds[0][tid], m_lds[1][tid]),
                       fmaxf(m_lds[2][tid], m_lds[3][tid]));
      atomicMax(&m_enc[g], encf(mm));
    }
  }
}

// ---------------- MLP ----------------

__global__ void k_mlp(const float* __restrict__ h2, const float* __restrict__ r2,
                      const float* __restrict__ s2,
                      const float* __restrict__ W1, const float* __restrict__ b1,
                      const float* __restrict__ W2, const float* __restrict__ b2,
                      const float* __restrict__ W3, const float* __restrict__ b3,
                      float* __restrict__ out) {
  __shared__ float x[4 * D], h1[32], h2s[16];
  int b = blockIdx.x, t = threadIdx.x;   // 128 threads
  x[t]       = (t < D) ? h2[b * D + t]         : r2[b * D + (t - D)] / s2[b];
  x[128 + t] = (t < D) ? h2[B * D + b * D + t] : r2[B * D + b * D + (t - D)] / s2[B + b];
  __syncthreads();
  if (t < 32) {
    float acc = b1[t];
    const float* w = W1 + (size_t)t * (4 * D);
    #pragma unroll 8
    for (int k = 0; k < 4 * D; ++k) acc += x[k] * w[k];
    h1[t] = fmaxf(acc, 0.0f);
  }
  __syncthreads();
  if (t < 16) {
    float acc = b2[t];
    const float* w = W2 + (size_t)t * 32;
    #pragma unroll
    for (int k = 0; k < 32; ++k) acc += h1[k] * w[k];
    h2s[t] = fmaxf(acc, 0.0f);
  }
  __syncthreads();
  if (t == 0) {
    float acc = b3[0];
    #pragma unroll
    for (int k = 0; k < 16; ++k) acc += h2s[k] * W3[k];
    out[b] = acc;
  }
}

// ---------------- driver ----------------

extern "C" void kernel_launch(void* const* d_in, const int* in_sizes, int n_in,
                              void* d_out, int out_size, void* d_ws, size_t ws_size,
                              hipStream_t stream) {
  const float* feat      = (const float*)d_in[0];
  const float* efeat     = (const float*)d_in[1];
  const int*   edge_dst  = (const int*)d_in[2];
  const int*   node_graph= (const int*)d_in[3];
  const float* node_Wih  = (const float*)d_in[5];
  const float* node_Whh  = (const float*)d_in[6];
  const float* node_bih  = (const float*)d_in[7];
  const float* node_bhh  = (const float*)d_in[8];
  const float* edge_Wih  = (const float*)d_in[9];
  const float* edge_Whh  = (const float*)d_in[10];
  const float* edge_bih  = (const float*)d_in[11];
  const float* edge_bhh  = (const float*)d_in[12];
  const float* W1 = (const float*)d_in[13];
  const float* b1 = (const float*)d_in[14];
  const float* W2 = (const float*)d_in[15];
  const float* b2 = (const float*)d_in[16];
  const float* W3 = (const float*)d_in[17];
  const float* b3 = (const float*)d_in[18];
  float* out = (float*)d_out;

  const int N = in_sizes[0] / D;
  const int E = in_sizes[2];

  // ws layout: zero-region first (deg, h2, c2) -> ONE small memset
  float* ws = (float*)d_ws;
  size_t off = 0;
  int* deg        = (int*)(ws + off); off += N;           // zeroed
  float* h2       = ws + off; off += 2 * B * D;           // zeroed
  float* c2       = ws + off; off += 2 * B * D;           // zeroed
  float* edge_agg = ws + off; off += (size_t)N * D;
  float* s2       = ws + off; off += 2 * B;
  float* r2       = ws + off; off += 2 * B * D;
  float* off2     = ws + off; off += 2 * B;
  unsigned* m2    = (unsigned*)(ws + off); off += 2 * B;
  int* row_start  = (int*)(ws + off); off += N;
  int* cursor     = (int*)(ws + off); off += N;
  int* blocksum   = (int*)(ws + off); off += 128;
  int* csr        = (int*)(ws + off); off += E + 8;

  hipMemsetAsync(ws, 0, ((size_t)N + 4 * B * D) * sizeof(float), stream);

  const int nb  = (N + SCAN_BS - 1) / SCAN_BS;
  const int DEG = (E + 255) / 256;
  const int ATT = (N + NPB - 1) / NPB;

  // CSR build (deg merged with both-side LSTM it0)
  k_deg_lstm<<<DEG + 128, 256, 0, stream>>>(DEG, edge_dst, deg, E, h2, c2, s2, r2, m2, off2,
      node_Wih, node_Whh, node_bih, node_bhh, edge_Wih, edge_Whh, edge_bih, edge_bhh);
  k_scan1<<<nb, SCAN_BS, 0, stream>>>(deg, row_start, blocksum, N);
  k_scan3<<<(N + 255) / 256, 256, 0, stream>>>(row_start, blocksum, cursor, N, nb);
  k_fill<<<DEG, 256, 0, stream>>>(edge_dst, cursor, csr, E);

  // gather: one 16-lane group per node, 16 groups per block
  k_gather<<<(N + 15) / 16, 256, 0, stream>>>(efeat, csr, row_start, deg, edge_agg, N);

  // set2set loop (LSTM it0 already done in k_deg_lstm)
  dim3 ga(ATT, 2), gb(B, 2);
  k_att_fused<<<ga, 256, 0, stream>>>(feat, edge_agg, node_graph, h2, off2, m2, s2, r2, N);
  for (int it = 1; it < 3; ++it) {
    k_lstm2<<<gb, 256, 0, stream>>>(0, h2, c2, s2, r2, m2, off2,
                                    node_Wih, node_Whh, node_bih, node_bhh,
                                    edge_Wih, edge_Whh, edge_bih, edge_bhh);
    k_att_fused<<<ga, 256, 0, stream>>>(feat, edge_agg, node_graph, h2, off2, m2, s2, r2, N);
  }

  k_mlp<<<B, 128, 0, stream>>>(h2, r2, s2, W1, b1, W2, b2, W3, b3, out);
}

// Round 13
// 261.010 us; speedup vs baseline: 1.0686x; 1.0610x over previous
//
#include <hip/hip_runtime.h>
#include <math.h>

#define D 64
#define B 64
#define NPB 128      // nodes per att block
#define NSLOT 4
#define SCAN_BS 1024

__device__ __forceinline__ unsigned encf(float x) {
  unsigned u = __float_as_uint(x);
  return (u & 0x80000000u) ? ~u : (u | 0x80000000u);
}
__device__ __forceinline__ float decf(unsigned e) {
  return (e & 0x80000000u) ? __uint_as_float(e ^ 0x80000000u) : __uint_as_float(~e);
}
__device__ __forceinline__ float sigm(float x) { return 1.0f / (1.0f + __expf(-x)); }

// ---------------- LSTM body ----------------

__device__ __forceinline__ void lstm_body(int side, int b, int first,
    float* __restrict__ h2, float* __restrict__ c2,
    float* __restrict__ s2, float* __restrict__ r2,
    unsigned* __restrict__ m2, float* __restrict__ off2,
    const float* __restrict__ nWih, const float* __restrict__ nWhh,
    const float* __restrict__ nbih, const float* __restrict__ nbhh,
    const float* __restrict__ eWih, const float* __restrict__ eWhh,
    const float* __restrict__ ebih, const float* __restrict__ ebhh,
    float* sq, float* sg) {
  const float* Wih = side ? eWih : nWih;
  const float* Whh = side ? eWhh : nWhh;
  const float* bih = side ? ebih : nbih;
  const float* bhh = side ? ebhh : nbhh;
  float* h = h2 + side * B * D;
  float* c = c2 + side * B * D;
  float* s_buf = s2 + side * B;
  float* r_buf = r2 + side * B * D;

  int j = threadIdx.x;
  if (j < D) {
    sq[j] = h[b * D + j];
  } else if (j < 2 * D) {
    sq[j] = first ? 0.0f : (r_buf[b * D + (j - D)] / s_buf[b]);
  }
  __syncthreads();
  float acc = bih[j] + bhh[j];
  const float* wr = Wih + (size_t)j * (2 * D);
  #pragma unroll 8
  for (int k = 0; k < 2 * D; ++k) acc += sq[k] * wr[k];
  const float* wr2 = Whh + (size_t)j * D;
  #pragma unroll 8
  for (int k = 0; k < D; ++k) acc += sq[k] * wr2[k];
  sg[j] = acc;
  __syncthreads();
  if (j < D) {
    float ig = sigm(sg[j]);
    float fg = sigm(sg[D + j]);
    float gg = tanhf(sg[2 * D + j]);
    float og = sigm(sg[3 * D + j]);
    float cn = fg * c[b * D + j] + ig * gg;
    c[b * D + j] = cn;
    h[b * D + j] = og * tanhf(cn);
    r_buf[b * D + j] = 0.0f;
  }
  if (j == D) s_buf[b] = 0.0f;
  if (j == D + 1) {
    int idx = side * B + b;
    off2[idx] = first ? 0.0f : decf(m2[idx]);   // exact: const offset cancels in alpha
    m2[idx] = 0u;
  }
}

// ---------------- CSR build ----------------

// merged: blocks [0,DEG) degree histogram; [DEG, DEG+128) LSTM it0 both sides
__global__ void k_deg_lstm(int DEG, const int* __restrict__ edge_dst, int* __restrict__ deg, int E,
                           float* __restrict__ h2, float* __restrict__ c2,
                           float* __restrict__ s2, float* __restrict__ r2,
                           unsigned* __restrict__ m2, float* __restrict__ off2,
                           const float* __restrict__ nWih, const float* __restrict__ nWhh,
                           const float* __restrict__ nbih, const float* __restrict__ nbhh,
                           const float* __restrict__ eWih, const float* __restrict__ eWhh,
                           const float* __restrict__ ebih, const float* __restrict__ ebhh) {
  __shared__ float sq[2 * D], sg[4 * D];
  int bx = blockIdx.x;
  if (bx < DEG) {
    int i = bx * 256 + threadIdx.x;
    if (i < E) atomicAdd(&deg[edge_dst[i]], 1);
  } else {
    int j = bx - DEG;            // 0..127
    lstm_body(j >> 6, j & 63, 1, h2, c2, s2, r2, m2, off2,
              nWih, nWhh, nbih, nbhh, eWih, eWhh, ebih, ebhh, sq, sg);
  }
}

__global__ void k_scan1(const int* __restrict__ deg, int* __restrict__ row_start,
                        int* __restrict__ blocksum, int N) {
  __shared__ int sm[SCAN_BS];
  int t = threadIdx.x;
  int base = blockIdx.x * SCAN_BS;
  int v = (base + t < N) ? deg[base + t] : 0;
  sm[t] = v;
  __syncthreads();
  for (int ofs = 1; ofs < SCAN_BS; ofs <<= 1) {
    int add = (t >= ofs) ? sm[t - ofs] : 0;
    __syncthreads();
    sm[t] += add;
    __syncthreads();
  }
  if (base + t < N) row_start[base + t] = sm[t] - v;
  if (t == SCAN_BS - 1) blocksum[blockIdx.x] = sm[t];
}

// scan3 with inline scan of blocksum
__global__ void k_scan3(int* __restrict__ row_start, const int* __restrict__ blocksum,
                        int* __restrict__ cursor, int N, int nb) {
  __shared__ int sm[128];
  int t = threadIdx.x;
  if (t < 128) sm[t] = (t < nb) ? blocksum[t] : 0;
  __syncthreads();
  for (int ofs = 1; ofs < 128; ofs <<= 1) {
    int add = (t < 128 && t >= ofs) ? sm[t - ofs] : 0;
    __syncthreads();
    if (t < 128) sm[t] += add;
    __syncthreads();
  }
  int n = blockIdx.x * 256 + t;
  if (n < N) {
    int c = n / SCAN_BS;
    int v = row_start[n] + ((c > 0) ? sm[c - 1] : 0);
    row_start[n] = v;
    cursor[n] = v;
  }
}

__global__ void k_fill(const int* __restrict__ edge_dst, int* __restrict__ cursor,
                       int* __restrict__ csr, int E) {
  int e = blockIdx.x * blockDim.x + threadIdx.x;
  if (e < E) {
    int dst = edge_dst[e];
    int idx = atomicAdd(&cursor[dst], 1);
    csr[idx] = e;
  }
}

// ---------------- gather (node-centric: 16-lane group/node, unroll 16) -------

__global__ void k_gather(const float* __restrict__ efeat, const int* __restrict__ csr,
                         const int* __restrict__ row_start, const int* __restrict__ deg,
                         float* __restrict__ edge_agg, int N) {
  int grp = (blockIdx.x * blockDim.x + threadIdx.x) >> 4;
  int l16 = threadIdx.x & 15;
  if (grp >= N) return;
  int base = row_start[grp];
  int dg = deg[grp];
  float4 acc = make_float4(0.f, 0.f, 0.f, 0.f);
  for (int i = 0; i < dg; i += 16) {
    int idx[16];
    #pragma unroll
    for (int j = 0; j < 16; ++j) {
      int k = i + j;
      idx[j] = csr[base + (k < dg ? k : dg - 1)];
    }
    #pragma unroll
    for (int j = 0; j < 16; ++j) {
      float4 v = *(const float4*)(efeat + (size_t)idx[j] * D + l16 * 4);
      bool ok = (i + j < dg);
      acc.x += ok ? v.x : 0.0f;
      acc.y += ok ? v.y : 0.0f;
      acc.z += ok ? v.z : 0.0f;
      acc.w += ok ? v.w : 0.0f;
    }
  }
  float inv = 1.0f / fmaxf((float)dg, 1.0f);
  acc.x *= inv; acc.y *= inv; acc.z *= inv; acc.w *= inv;
  *(float4*)(edge_agg + (size_t)grp * D + l16 * 4) = acc;
}

// ---------------- standalone LSTM (both sides, grid (B,2)) -------------------

__global__ void k_lstm2(int first, float* __restrict__ h2, float* __restrict__ c2,
                        float* __restrict__ s2, float* __restrict__ r2,
                        unsigned* __restrict__ m2, float* __restrict__ off2,
                        const float* __restrict__ nWih, const float* __restrict__ nWhh,
                        const float* __restrict__ nbih, const float* __restrict__ nbhh,
                        const float* __restrict__ eWih, const float* __restrict__ eWhh,
                        const float* __restrict__ ebih, const float* __restrict__ ebhh) {
  __shared__ float sq[2 * D], sg[4 * D];
  lstm_body(blockIdx.y, blockIdx.x, first, h2, c2, s2, r2, m2, off2,
            nWih, nWhh, nbih, nbhh, eWih, eWhh, ebih, ebhh, sq, sg);
}

// ---------------- fused one-pass attention (R9 LDS-slot + gid staging) -------
// grid (ceil(N/NPB), 2), 256 threads (16 groups x 16 lanes).

__global__ void k_att_fused(const float* __restrict__ feat, const float* __restrict__ edge_agg,
                            const int* __restrict__ gid, const float* __restrict__ h2,
                            const float* __restrict__ off2, unsigned* __restrict__ m2,
                            float* __restrict__ s2, float* __restrict__ r2, int N) {
  __shared__ float r_lds[16 * NSLOT * D];   // 16KB
  __shared__ float s_lds[16 * NSLOT];
  __shared__ float m_lds[16 * NSLOT];
  __shared__ float h_lds[NSLOT * D];
  __shared__ float o_lds[NSLOT];
  __shared__ int gid_lds[NPB];
  __shared__ int used[NSLOT];

  int side = blockIdx.y;
  const float* F = side ? edge_agg : feat;
  const float* h = h2 + side * B * D;
  const float* off = off2 + side * B;
  unsigned* m_enc = m2 + side * B;
  float* s_buf = s2 + side * B;
  float* r_buf = r2 + side * B * D;

  int tid = threadIdx.x;
  int grp = tid >> 4;
  int d4  = tid & 15;
  int base = blockIdx.x * NPB;

  for (int i = tid; i < 16 * NSLOT * D; i += 256) r_lds[i] = 0.0f;
  if (tid < 16 * NSLOT) { s_lds[tid] = 0.0f; m_lds[tid] = -3.4e38f; }
  if (tid < NSLOT) used[tid] = 0;
  if (tid < NPB) gid_lds[tid] = gid[min(base + tid, N - 1)];   // clamped stage
  __syncthreads();
  const int gfirst = gid_lds[0];
  {
    int slot = tid >> 6, dim = tid & 63;
    int g = gfirst + slot;
    if (g < B) {
      h_lds[tid] = h[g * D + dim];
      if (dim == 0) o_lds[slot] = off[g];
    }
  }
  __syncthreads();

  float4 acc = make_float4(0.f, 0.f, 0.f, 0.f);
  float sum_ex = 0.0f;
  float local_max = -3.4e38f;
  int cur_g = -1;

  for (int it = 0; it < NPB / 32; ++it) {
    int p0 = it * 32 + grp;
    int n0 = base + p0;
    int n1 = n0 + 16;
    bool ok0 = n0 < N, ok1 = n1 < N;
    int g0 = gid_lds[p0];
    int g1 = gid_lds[p0 + 16];
    float4 f0 = make_float4(0,0,0,0), f1 = make_float4(0,0,0,0);
    float dot0 = 0.f, dot1 = 0.f, ex0 = 0.f, ex1 = 0.f;
    if (ok0) {
      f0 = *(const float4*)(F + (size_t)n0 * D + d4 * 4);
      int s0 = g0 - gfirst;
      float4 hv = (s0 >= 0 && s0 < NSLOT) ? *(const float4*)&h_lds[(s0 << 6) + (d4 << 2)]
                                          : *(const float4*)(h + (size_t)g0 * D + d4 * 4);
      dot0 = f0.x * hv.x + f0.y * hv.y + f0.z * hv.z + f0.w * hv.w;
    }
    if (ok1) {
      f1 = *(const float4*)(F + (size_t)n1 * D + d4 * 4);
      int s1 = g1 - gfirst;
      float4 hv = (s1 >= 0 && s1 < NSLOT) ? *(const float4*)&h_lds[(s1 << 6) + (d4 << 2)]
                                          : *(const float4*)(h + (size_t)g1 * D + d4 * 4);
      dot1 = f1.x * hv.x + f1.y * hv.y + f1.z * hv.z + f1.w * hv.w;
    }
    dot0 += __shfl_xor(dot0, 1); dot1 += __shfl_xor(dot1, 1);
    dot0 += __shfl_xor(dot0, 2); dot1 += __shfl_xor(dot1, 2);
    dot0 += __shfl_xor(dot0, 4); dot1 += __shfl_xor(dot1, 4);
    dot0 += __shfl_xor(dot0, 8); dot1 += __shfl_xor(dot1, 8);
    if (ok0) {
      int s0 = g0 - gfirst;
      ex0 = __expf(dot0 - ((s0 >= 0 && s0 < NSLOT) ? o_lds[s0] : off[g0]));
    }
    if (ok1) {
      int s1 = g1 - gfirst;
      ex1 = __expf(dot1 - ((s1 >= 0 && s1 < NSLOT) ? o_lds[s1] : off[g1]));
    }

    #pragma unroll
    for (int pair = 0; pair < 2; ++pair) {
      bool ok = pair ? ok1 : ok0;
      int g = pair ? g1 : g0;
      float ex = pair ? ex1 : ex0;
      float dt = pair ? dot1 : dot0;
      float4 f = pair ? f1 : f0;
      if (!ok) continue;
      if (g != cur_g) {
        if (cur_g >= 0) {
          int slot = cur_g - gfirst;
          if (slot >= 0 && slot < NSLOT) {
            float4* p = (float4*)&r_lds[((grp * NSLOT + slot) << 6) + (d4 << 2)];
            float4 v = *p;
            v.x += acc.x; v.y += acc.y; v.z += acc.z; v.w += acc.w;
            *p = v;
            if (d4 == 0) {
              s_lds[grp * NSLOT + slot] += sum_ex;
              m_lds[grp * NSLOT + slot] = fmaxf(m_lds[grp * NSLOT + slot], local_max);
              used[slot] = 1;
            }
          } else {
            float* rp = r_buf + cur_g * D + d4 * 4;
            atomicAdd(rp + 0, acc.x); atomicAdd(rp + 1, acc.y);
            atomicAdd(rp + 2, acc.z); atomicAdd(rp + 3, acc.w);
            if (d4 == 0) { atomicAdd(&s_buf[cur_g], sum_ex); atomicMax(&m_enc[cur_g], encf(local_max)); }
          }
        }
        cur_g = g; acc = make_float4(0,0,0,0); sum_ex = 0.f; local_max = -3.4e38f;
      }
      acc.x += ex * f.x; acc.y += ex * f.y; acc.z += ex * f.z; acc.w += ex * f.w;
      if (d4 == 0) { sum_ex += ex; local_max = fmaxf(local_max, dt); }
    }
  }
  // tail flush
  if (cur_g >= 0) {
    int slot = cur_g - gfirst;
    if (slot >= 0 && slot < NSLOT) {
      float4* p = (float4*)&r_lds[((grp * NSLOT + slot) << 6) + (d4 << 2)];
      float4 v = *p;
      v.x += acc.x; v.y += acc.y; v.z += acc.z; v.w += acc.w;
      *p = v;
      if (d4 == 0) {
        s_lds[grp * NSLOT + slot] += sum_ex;
        m_lds[grp * NSLOT + slot] = fmaxf(m_lds[grp * NSLOT + slot], local_max);
        used[slot] = 1;
      }
    } else {
      float* rp = r_buf + cur_g * D + d4 * 4;
      atomicAdd(rp + 0, acc.x); atomicAdd(rp + 1, acc.y);
      atomicAdd(rp + 2, acc.z); atomicAdd(rp + 3, acc.w);
      if (d4 == 0) { atomicAdd(&s_buf[cur_g], sum_ex); atomicMax(&m_enc[cur_g], encf(local_max)); }
    }
  }
  __syncthreads();

  // block-level reduction
  {
    int slot = tid >> 6, dim = tid & 63;
    int g = gfirst + slot;
    if (g < B && used[slot]) {
      float sum = 0.0f;
      #pragma unroll
      for (int q = 0; q < 16; ++q) sum += r_lds[((q * NSLOT + slot) << 6) + dim];
      atomicAdd(&r_buf[g * D + dim], sum);
    }
  }
  if (tid < NSLOT) {
    int g = gfirst + tid;
    if (g < B && used[tid]) {
      float ssum = 0.0f;
      #pragma unroll
      for (int q = 0; q < 16; ++q) ssum += s_lds[q * NSLOT + tid];
      atomicAdd(&s_buf[g], ssum);
    }
  } else if (tid >= 64 && tid < 64 + NSLOT) {
    int slot = tid - 64;
    int g = gfirst + slot;
    if (g < B && used[slot]) {
      float mmax = -3.4e38f;
      #pragma unroll
      for (int q = 0; q < 16; ++q) mmax = fmaxf(mmax, m_lds[q * NSLOT + slot]);
      atomicMax(&m_enc[g], encf(mmax));
    }
  }
}

// ---------------- MLP ----------------

__global__ void k_mlp(const float* __restrict__ h2, const float* __restrict__ r2,
                      const float* __restrict__ s2,
                      const float* __restrict__ W1, const float* __restrict__ b1,
                      const float* __restrict__ W2, const float* __restrict__ b2,
                      const float* __restrict__ W3, const float* __restrict__ b3,
                      float* __restrict__ out) {
  __shared__ float x[4 * D], h1[32], h2s[16];
  int b = blockIdx.x, t = threadIdx.x;   // 128 threads
  x[t]       = (t < D) ? h2[b * D + t]         : r2[b * D + (t - D)] / s2[b];
  x[128 + t] = (t < D) ? h2[B * D + b * D + t] : r2[B * D + b * D + (t - D)] / s2[B + b];
  __syncthreads();
  if (t < 32) {
    float acc = b1[t];
    const float* w = W1 + (size_t)t * (4 * D);
    #pragma unroll 8
    for (int k = 0; k < 4 * D; ++k) acc += x[k] * w[k];
    h1[t] = fmaxf(acc, 0.0f);
  }
  __syncthreads();
  if (t < 16) {
    float acc = b2[t];
    const float* w = W2 + (size_t)t * 32;
    #pragma unroll
    for (int k = 0; k < 32; ++k) acc += h1[k] * w[k];
    h2s[t] = fmaxf(acc, 0.0f);
  }
  __syncthreads();
  if (t == 0) {
    float acc = b3[0];
    #pragma unroll
    for (int k = 0; k < 16; ++k) acc += h2s[k] * W3[k];
    out[b] = acc;
  }
}

// ---------------- driver ----------------

extern "C" void kernel_launch(void* const* d_in, const int* in_sizes, int n_in,
                              void* d_out, int out_size, void* d_ws, size_t ws_size,
                              hipStream_t stream) {
  const float* feat      = (const float*)d_in[0];
  const float* efeat     = (const float*)d_in[1];
  const int*   edge_dst  = (const int*)d_in[2];
  const int*   node_graph= (const int*)d_in[3];
  const float* node_Wih  = (const float*)d_in[5];
  const float* node_Whh  = (const float*)d_in[6];
  const float* node_bih  = (const float*)d_in[7];
  const float* node_bhh  = (const float*)d_in[8];
  const float* edge_Wih  = (const float*)d_in[9];
  const float* edge_Whh  = (const float*)d_in[10];
  const float* edge_bih  = (const float*)d_in[11];
  const float* edge_bhh  = (const float*)d_in[12];
  const float* W1 = (const float*)d_in[13];
  const float* b1 = (const float*)d_in[14];
  const float* W2 = (const float*)d_in[15];
  const float* b2 = (const float*)d_in[16];
  const float* W3 = (const float*)d_in[17];
  const float* b3 = (const float*)d_in[18];
  float* out = (float*)d_out;

  const int N = in_sizes[0] / D;
  const int E = in_sizes[2];

  // ws layout: zero-region first (deg, h2, c2) -> ONE small memset
  float* ws = (float*)d_ws;
  size_t off = 0;
  int* deg        = (int*)(ws + off); off += N;           // zeroed
  float* h2       = ws + off; off += 2 * B * D;           // zeroed
  float* c2       = ws + off; off += 2 * B * D;           // zeroed
  float* edge_agg = ws + off; off += (size_t)N * D;
  float* s2       = ws + off; off += 2 * B;
  float* r2       = ws + off; off += 2 * B * D;
  float* off2     = ws + off; off += 2 * B;
  unsigned* m2    = (unsigned*)(ws + off); off += 2 * B;
  int* row_start  = (int*)(ws + off); off += N;
  int* cursor     = (int*)(ws + off); off += N;
  int* blocksum   = (int*)(ws + off); off += 128;
  int* csr        = (int*)(ws + off); off += E + 8;

  hipMemsetAsync(ws, 0, ((size_t)N + 4 * B * D) * sizeof(float), stream);

  const int nb  = (N + SCAN_BS - 1) / SCAN_BS;
  const int DEG = (E + 255) / 256;
  const int ATT = (N + NPB - 1) / NPB;

  // CSR build (deg merged with both-side LSTM it0)
  k_deg_lstm<<<DEG + 128, 256, 0, stream>>>(DEG, edge_dst, deg, E, h2, c2, s2, r2, m2, off2,
      node_Wih, node_Whh, node_bih, node_bhh, edge_Wih, edge_Whh, edge_bih, edge_bhh);
  k_scan1<<<nb, SCAN_BS, 0, stream>>>(deg, row_start, blocksum, N);
  k_scan3<<<(N + 255) / 256, 256, 0, stream>>>(row_start, blocksum, cursor, N, nb);
  k_fill<<<DEG, 256, 0, stream>>>(edge_dst, cursor, csr, E);

  // gather: one 16-lane group per node, 16 groups per block
  k_gather<<<(N + 15) / 16, 256, 0, stream>>>(efeat, csr, row_start, deg, edge_agg, N);

  // set2set loop (LSTM it0 already done in k_deg_lstm)
  dim3 ga(ATT, 2), gb(B, 2);
  k_att_fused<<<ga, 256, 0, stream>>>(feat, edge_agg, node_graph, h2, off2, m2, s2, r2, N);
  for (int it = 1; it < 3; ++it) {
    k_lstm2<<<gb, 256, 0, stream>>>(0, h2, c2, s2, r2, m2, off2,
                                    node_Wih, node_Whh, node_bih, node_bhh,
                                    edge_Wih, edge_Whh, edge_bih, edge_bhh);
    k_att_fused<<<ga, 256, 0, stream>>>(feat, edge_agg, node_graph, h2, off2, m2, s2, r2, N);
  }

  k_mlp<<<B, 128, 0, stream>>>(h2, r2, s2, W1, b1, W2, b2, W3, b3, out);
}